// Round 17
// baseline (230.140 us; speedup 1.0000x reference)
//
#include <hip/hip_runtime.h>
#include <hip/hip_fp16.h>

#define NN 8192
#define DDIM 128
#define DELTA 0.010f    // >= 2*delta_wc; delta_wc <= 2^-8 (bf16 MFMA) + 5e-4 (f16 store)
#define MAXC 256
#define SIMSTRIDE 16384 // ushorts per row slot (= 32 KB = one f32 output row)

typedef short short8 __attribute__((ext_vector_type(8)));
typedef unsigned short ushort8 __attribute__((ext_vector_type(8)));
typedef float f32x16 __attribute__((ext_vector_type(16)));

__device__ __forceinline__ ushort bf16_rne(float v) {
    const unsigned x = __float_as_uint(v);
    return (ushort)((x + 0x7FFFu + ((x >> 16) & 1u)) >> 16);
}

// ---------------- Kernel 1: MLP (Linear->ReLU->Linear) + L2 normalize + bf16 copy ----
// f32 emb path FROZEN (bit-exact vs round-3/5 passing version); RNE bf16 mirror.
__global__ __launch_bounds__(128, 1)
void mlp_norm_kernel(const float* __restrict__ X, const float* __restrict__ W1,
                     const float* __restrict__ b1, const float* __restrict__ W2,
                     const float* __restrict__ b2, float* __restrict__ emb,
                     ushort* __restrict__ ebh, int rowsPerBlock)
{
    const int t = threadIdx.x;
    float4 w1r[32], w2r[32];
#pragma unroll
    for (int i = 0; i < 32; ++i) w1r[i] = *(const float4*)&W1[t * DDIM + i * 4];
#pragma unroll
    for (int i = 0; i < 32; ++i) w2r[i] = *(const float4*)&W2[t * DDIM + i * 4];
    const float bb1 = b1[t], bb2 = b2[t];

    __shared__ float sx[DDIM];
    __shared__ float sh[DDIM];
    __shared__ float wred[2];

    const int row0 = blockIdx.x * rowsPerBlock;
    for (int r = 0; r < rowsPerBlock; ++r) {
        const int row = row0 + r;
        sx[t] = X[(size_t)row * DDIM + t];
        __syncthreads();
        float acc = bb1;
#pragma unroll
        for (int i = 0; i < 32; ++i) {
            const float4 xv = *(const float4*)&sx[i * 4];
            acc = fmaf(xv.x, w1r[i].x, acc);
            acc = fmaf(xv.y, w1r[i].y, acc);
            acc = fmaf(xv.z, w1r[i].z, acc);
            acc = fmaf(xv.w, w1r[i].w, acc);
        }
        sh[t] = fmaxf(acc, 0.f);
        __syncthreads();
        float acc2 = bb2;
#pragma unroll
        for (int i = 0; i < 32; ++i) {
            const float4 hv = *(const float4*)&sh[i * 4];
            acc2 = fmaf(hv.x, w2r[i].x, acc2);
            acc2 = fmaf(hv.y, w2r[i].y, acc2);
            acc2 = fmaf(hv.z, w2r[i].z, acc2);
            acc2 = fmaf(hv.w, w2r[i].w, acc2);
        }
        float sq = acc2 * acc2;
#pragma unroll
        for (int off = 1; off < 64; off <<= 1) sq += __shfl_xor(sq, off);
        if ((t & 63) == 0) wred[t >> 6] = sq;
        __syncthreads();
        const float ss = wred[0] + wred[1];
        const float inv = 1.0f / fmaxf(sqrtf(ss), 1e-12f);
        const float v = acc2 * inv;
        emb[(size_t)row * DDIM + t] = v;
        ebh[(size_t)row * DDIM + t] = bf16_rne(v);
        __syncthreads();   // protect sx/sh/wred for next iteration
    }
}

// ---------------- Kernel 2: approx sim = ebh @ ebh^T (bf16 MFMA, f16 store in d_out) --
// BYTE-EXACT round-12 version (proven: scalar 2B stores fine, repack costs +2.9us).
__global__ __launch_bounds__(256)
void simgemm_bf16(const ushort* __restrict__ ebh, ushort* __restrict__ sim)
{
    __shared__ ushort lA[128 * 128];
    __shared__ ushort lB[128 * 128];

    const int tid = threadIdx.x;
    const int bi = blockIdx.x & 63, bj = blockIdx.x >> 6;
    const int m0 = bi << 7, n0 = bj << 7;
    const int lane = tid & 63, wid = tid >> 6;
    const int wr = wid >> 1, wc = wid & 1;
    const int frow = lane & 31, fsel = lane >> 5;

    const int srow0 = tid >> 4, sg = tid & 15;
#pragma unroll
    for (int i = 0; i < 8; ++i) {
        const int row = srow0 + i * 16;
        const int so = row * 128 + ((sg ^ (row & 15)) << 3);
        *(uint4*)&lA[so] = *(const uint4*)&ebh[(size_t)(m0 + row) * DDIM + sg * 8];
        *(uint4*)&lB[so] = *(const uint4*)&ebh[(size_t)(n0 + row) * DDIM + sg * 8];
    }
    __syncthreads();

    f32x16 acc[2][2];
#pragma unroll
    for (int mb = 0; mb < 2; ++mb)
#pragma unroll
        for (int nb = 0; nb < 2; ++nb)
#pragma unroll
            for (int q = 0; q < 16; ++q) acc[mb][nb][q] = 0.f;

#pragma unroll
    for (int ks = 0; ks < 8; ++ks) {
        const int g = ks * 2 + fsel;
        short8 av[2], bv[2];
#pragma unroll
        for (int mb = 0; mb < 2; ++mb) {
            const int r = wr * 64 + mb * 32 + frow;
            av[mb] = *(const short8*)&lA[r * 128 + ((g ^ (r & 15)) << 3)];
        }
#pragma unroll
        for (int nb = 0; nb < 2; ++nb) {
            const int r = wc * 64 + nb * 32 + frow;
            bv[nb] = *(const short8*)&lB[r * 128 + ((g ^ (r & 15)) << 3)];
        }
#pragma unroll
        for (int mb = 0; mb < 2; ++mb)
#pragma unroll
            for (int nb = 0; nb < 2; ++nb)
                acc[mb][nb] = __builtin_amdgcn_mfma_f32_32x32x16_bf16(
                    av[mb], bv[nb], acc[mb][nb], 0, 0, 0);
    }

    // C/D layout: col = lane&31, row = (q&3) + 8*(q>>2) + 4*(lane>>5)  [verified r7-r16]
#pragma unroll
    for (int mb = 0; mb < 2; ++mb)
#pragma unroll
        for (int nb = 0; nb < 2; ++nb)
#pragma unroll
            for (int q = 0; q < 16; ++q) {
                const int rl = (q & 3) + 8 * (q >> 2) + 4 * fsel;
                const int grow = m0 + wr * 64 + mb * 32 + rl;
                const int gcol = n0 + wc * 64 + nb * 32 + (lane & 31);
                sim[(size_t)grow * SIMSTRIDE + gcol] =
                    __half_as_ushort(__float2half_rn(acc[mb][nb][q]));
            }
}

// ---------------- Kernel 3: top-kp1 on f16 sims (2-level histogram select) + fixup ----
// Select/window/write BYTE-EXACT round-12 (best measured select). SINGLE CHANGE: the
// exact-dot fixup is parallelized 4 lanes/candidate (contiguous 32-elem serial chunks,
// float4 loads, 2x shfl_xor pairwise fold) instead of 1 thread/candidate scalar chain
// -- removes the ~2-3K-cycle near-idle phase per row. Dot rounding differs ~1e-7
// (same class as serial-vs-numpy, passed 7 rounds; rank gap ~9.6e-4).
__global__ __launch_bounds__(256)
void topk_relu_kernel(float* __restrict__ out, const float* __restrict__ emb,
                      const int* __restrict__ kp1p)
{
    const int row = blockIdx.x;
    const int t = threadIdx.x;
    const int w = t >> 6;
    const int lane = t & 63;
    const unsigned kp1 = (unsigned)kp1p[0];
    const ushort* simrow = (const ushort*)out + (size_t)row * SIMSTRIDE;
    float* rowp = out + (size_t)row * NN;

    __shared__ unsigned bitmap[NN / 32];
    __shared__ float semb[DDIM];
    __shared__ unsigned hist[4][256];
    __shared__ unsigned h2[64];
    __shared__ unsigned wpart[4];
    __shared__ unsigned sBA[4];     // 0: binB, 1: A(above), 2: teff, 3: keepall flag
    __shared__ int cidx[MAXC];
    __shared__ float cval[MAXC];
    __shared__ int cnum;

    bitmap[t] = 0;
    hist[0][t] = 0; hist[1][t] = 0; hist[2][t] = 0; hist[3][t] = 0;
    if (t < 64) h2[t] = 0;
    if (t < 4) sBA[t] = 0;
    if (t == 0) cnum = 0;
    if (t < DDIM) semb[t] = emb[(size_t)row * DDIM + t];
    __syncthreads();

    // load 32 f16/thread (coalesced 16B), zero non-positives, level-1 histogram
    unsigned u[32];
#pragma unroll
    for (int i = 0; i < 4; ++i) {
        const ushort8 v8 = *(const ushort8*)&simrow[i * 2048 + t * 8];
#pragma unroll
        for (int j = 0; j < 8; ++j) {
            const unsigned uu = (v8[j] < 0x8000u) ? (unsigned)v8[j] : 0u;
            u[i * 8 + j] = uu;
            if (uu) atomicAdd(&hist[w][uu >> 6], 1u);
        }
    }
    __syncthreads();

    // ---- level-1: suffix scan over 256 bins (thread t owns bin t) ----
    const unsigned tot = hist[0][t] + hist[1][t] + hist[2][t] + hist[3][t];
    unsigned s = tot;
#pragma unroll
    for (int off = 1; off < 64; off <<= 1) {
        const unsigned o = __shfl_down(s, off);
        if (lane + off < 64) s += o;
    }
    if (lane == 0) wpart[w] = s;
    __syncthreads();
    unsigned addhi = 0;
    for (int w2 = w + 1; w2 < 4; ++w2) addhi += wpart[w2];
    const unsigned S = s + addhi;               // inclusive suffix: count(bin >= t)
    if (S >= kp1 && S - tot < kp1) { sBA[0] = (unsigned)t; sBA[1] = S - tot; }
    if (t == 0 && wpart[0] + wpart[1] + wpart[2] + wpart[3] < kp1) sBA[3] = 1u;
    __syncthreads();

    const bool keepall = (sBA[3] != 0u);
    if (!keepall) {
        // ---- level-2: 64-bin histogram of bin-B values' low 6 bits ----
        const unsigned binB = sBA[0];
#pragma unroll
        for (int q = 0; q < 32; ++q)
            if (u[q] && (u[q] >> 6) == binB) atomicAdd(&h2[u[q] & 63u], 1u);
        __syncthreads();
        if (t < 64) {
            const unsigned need = kp1 - sBA[1];
            const unsigned h = h2[t];
            unsigned s2 = h;
#pragma unroll
            for (int off = 1; off < 64; off <<= 1) {
                const unsigned o = __shfl_down(s2, off);
                if (t + off < 64) s2 += o;
            }
            if (s2 >= need && s2 - h < need) sBA[2] = (binB << 6) | (unsigned)t;
        }
        __syncthreads();
    }

    // ---- fixup window (identical to r12) ----
    unsigned hi16, lo16;
    if (!keepall) {
        const unsigned teff = sBA[2];
        const float Treal = __half2float(__ushort_as_half((ushort)teff));
        hi16 = (unsigned)__half_as_ushort(__float2half_rn(Treal + DELTA)) + 1u;
        const float loR = Treal - DELTA;
        if (loR <= 0.f) lo16 = 1u;
        else {
            const unsigned l = __half_as_ushort(__float2half_rn(loR));
            lo16 = (l > 1u) ? l - 1u : 1u;
        }

        unsigned acnt = 0;
#pragma unroll
        for (int q = 0; q < 32; ++q) {
            const unsigned uu = u[q];
            if (uu > hi16) ++acnt;
            else if (uu >= lo16) {
                const int p = atomicAdd(&cnum, 1);
                if (p < MAXC) cidx[p] = (q >> 3) * 2048 + t * 8 + (q & 7);
            }
        }
#pragma unroll
        for (int off = 1; off < 64; off <<= 1) acnt += __shfl_xor(acnt, off);
        if (lane == 0) wpart[w] = acnt;
        __syncthreads();
        const unsigned A = wpart[0] + wpart[1] + wpart[2] + wpart[3];
        const int nc = cnum < MAXC ? cnum : MAXC;

        // exact dots, PARALLEL: 4 lanes/candidate, contiguous 32-elem serial chunks
        // (float4 loads), pairwise fold. Error class ~1e-7, same as serial-vs-numpy.
        const int sub = t & 3;
        for (int j = (t >> 2); j < nc; j += 64) {
            const float* rb = emb + (size_t)cidx[j] * DDIM + sub * 32;
            const float* se = &semb[sub * 32];
            float a = 0.f;
#pragma unroll
            for (int k = 0; k < 32; k += 4) {
                const float4 rv = *(const float4*)&rb[k];
                a = fmaf(se[k + 0], rv.x, a);
                a = fmaf(se[k + 1], rv.y, a);
                a = fmaf(se[k + 2], rv.z, a);
                a = fmaf(se[k + 3], rv.w, a);
            }
            a += __shfl_xor(a, 1);
            a += __shfl_xor(a, 2);
            if (sub == 0) cval[j] = a;
        }
        __syncthreads();
        // rank among candidates (ties -> lower index wins, matching lax.top_k)
        if (t < nc) {
            const float e = cval[t];
            const int my = cidx[t];
            int r = 0;
            for (int d = 0; d < nc; ++d)
                r += (cval[d] > e) || (cval[d] == e && cidx[d] < my);
            if (A + (unsigned)r < kp1)
                atomicOr(&bitmap[my >> 5], 1u << (my & 31));
        }
        __syncthreads();
    } else {
        hi16 = 0u;       // fewer than kp1 positives: keep all positives (v > 0)
        lo16 = 0xFFFFu;  // disable window path
        __syncthreads();
    }

    // ---- write full f32 row: certain-aboves + ranked-in candidates; zeros elsewhere --
#pragma unroll
    for (int i = 0; i < 4; ++i) {
        const int col0 = i * 2048 + t * 8;
        float o[8];
#pragma unroll
        for (int j = 0; j < 8; ++j) {
            const unsigned uu = u[i * 8 + j];
            const int idx = col0 + j;
            const bool keep = (uu > hi16) ||
                              (uu >= lo16 &&
                               ((bitmap[idx >> 5] >> (idx & 31)) & 1u));
            o[j] = keep ? __half2float(__ushort_as_half((ushort)uu)) : 0.f;
        }
        *(float4*)&rowp[col0]     = make_float4(o[0], o[1], o[2], o[3]);
        *(float4*)&rowp[col0 + 4] = make_float4(o[4], o[5], o[6], o[7]);
    }
}

extern "C" void kernel_launch(void* const* d_in, const int* in_sizes, int n_in,
                              void* d_out, int out_size, void* d_ws, size_t ws_size,
                              hipStream_t stream)
{
    const float* X  = (const float*)d_in[0];
    const float* W1 = (const float*)d_in[1];
    const float* b1 = (const float*)d_in[2];
    const float* W2 = (const float*)d_in[3];
    const float* b2 = (const float*)d_in[4];
    const int* kp1  = (const int*)d_in[5];
    float* out = (float*)d_out;
    float* emb  = (float*)d_ws;                                   // 4 MB f32
    ushort* ebh = (ushort*)((char*)d_ws + (size_t)NN * DDIM * 4); // 2 MB bf16

    mlp_norm_kernel<<<512, 128, 0, stream>>>(X, W1, b1, W2, b2, emb, ebh, 16);
    simgemm_bf16<<<4096, 256, 0, stream>>>(ebh, (ushort*)out);
    topk_relu_kernel<<<NN, 256, 0, stream>>>(out, emb, kp1);
}